// Round 1
// baseline (781.777 us; speedup 1.0000x reference)
//
#include <hip/hip_runtime.h>

// GCN on MI355X. Plan:
//  - Layer-1 propagation is rank-1 (x is [N,1]) -> pure scalar edge scatters.
//  - Layer-2 uses P(H W2) = (P H) W2: aggregate 128-dim h1, then GEMM.
//  - CSR-by-dst (counting sort) -> atomic-free wave-per-node aggregation.
//  - Two fp32 tiled GEMMs (no fp32 MFMA on CDNA4), wave-per-node final dot.
// ws layout: g1[N*128] (reused as h3) | z[N*128] | h2[N*256] | scalars | CSR.

#define HD 128
#define HD2 256

static inline size_t align256(size_t x) { return (x + 255) & ~(size_t)255; }

// Canonicalize edge_index to int32 src/dst. Harness may deliver int64 (reference
// dtype) or int32 (JAX x64-disabled canonicalization). Node ids < 2^31 and
// nonneg, so under an int64 layout the hi words (odd int32 indices) are all 0.
__global__ void k_cvt_edges(const int* __restrict__ ei, int* __restrict__ src32,
                            int* __restrict__ dst32, int E) {
    int e = blockIdx.x * blockDim.x + threadIdx.x;
    if (e >= E) return;
    bool is64 = (ei[1] == 0) && (ei[3] == 0) && (ei[5] == 0) && (ei[7] == 0);
    if (is64) { src32[e] = ei[2 * e];  dst32[e] = ei[2 * (E + e)]; }
    else      { src32[e] = ei[e];      dst32[e] = ei[E + e]; }
}

// ws is re-poisoned 0xAA before every launch: init everything we accumulate into.
__global__ void k_init(float* __restrict__ deg, float* __restrict__ q,
                       int* __restrict__ cnt, int N) {
    int i = blockIdx.x * blockDim.x + threadIdx.x;
    if (i < N) { deg[i] = 1.0f; q[i] = 0.0f; cnt[i] = 0; }  // deg starts at 1 (self loop)
}

__global__ void k_deg(const int* __restrict__ dst, const float* __restrict__ w,
                      float* __restrict__ deg, int* __restrict__ cnt, int E) {
    int e = blockIdx.x * blockDim.x + threadIdx.x;
    if (e < E) {
        int d = dst[e];
        atomicAdd(&deg[d], w[e]);
        atomicAdd(&cnt[d], 1);
    }
}

__global__ void k_pdis(const float* __restrict__ x, const float* __restrict__ deg,
                       float* __restrict__ dis, float* __restrict__ p, int N) {
    int i = blockIdx.x * blockDim.x + threadIdx.x;
    if (i < N) {
        float r = rsqrtf(deg[i]);  // deg >= 1 always (self loop, w >= 0)
        dis[i] = r;
        p[i] = r * x[i];
    }
}

__global__ void k_q(const int* __restrict__ src, const int* __restrict__ dst,
                    const float* __restrict__ w, const float* __restrict__ p,
                    float* __restrict__ q, int E) {
    int e = blockIdx.x * blockDim.x + threadIdx.x;
    if (e < E) atomicAdd(&q[dst[e]], w[e] * p[src[e]]);
}

// --- 3-kernel exclusive scan of cnt[0..N) -> rowptr[0..N] ---
__global__ __launch_bounds__(1024) void k_scan1(const int* __restrict__ cnt,
                                                int* __restrict__ incl,
                                                int* __restrict__ bsum, int N) {
    __shared__ int s[1024];
    int t = threadIdx.x, i = blockIdx.x * 1024 + t;
    s[t] = (i < N) ? cnt[i] : 0;
    __syncthreads();
    for (int off = 1; off < 1024; off <<= 1) {
        int add = (t >= off) ? s[t - off] : 0;
        __syncthreads();
        s[t] += add;
        __syncthreads();
    }
    if (i < N) incl[i] = s[t];
    if (t == 1023) bsum[blockIdx.x] = s[t];
}

__global__ void k_scan2(int* __restrict__ bsum, int nb) {
    __shared__ int s[1024];
    int t = threadIdx.x;
    for (int i = t; i < nb; i += blockDim.x) s[i] = bsum[i];
    __syncthreads();
    if (t == 0) {
        int run = 0;
        for (int i = 0; i < nb; i++) { int v = s[i]; s[i] = run; run += v; }
    }
    __syncthreads();
    for (int i = t; i < nb; i += blockDim.x) bsum[i] = s[i];
}

__global__ void k_scan3(const int* __restrict__ cnt, const int* __restrict__ incl,
                        const int* __restrict__ bsum, int* __restrict__ rowptr,
                        int* __restrict__ fill, int N, int E) {
    int i = blockIdx.x * blockDim.x + threadIdx.x;
    if (i < N) {
        rowptr[i] = bsum[i >> 10] + incl[i] - cnt[i];
        fill[i] = 0;
    }
    if (i == N) rowptr[N] = E;
}

__global__ void k_fill(const int* __restrict__ src, const int* __restrict__ dst,
                       const float* __restrict__ w, const int* __restrict__ rowptr,
                       int* __restrict__ fill, int* __restrict__ col,
                       float* __restrict__ val, int E) {
    int e = blockIdx.x * blockDim.x + threadIdx.x;
    if (e < E) {
        int d = dst[e];
        int pos = rowptr[d] + atomicAdd(&fill[d], 1);
        col[pos] = src[e];
        val[pos] = w[e];
    }
}

// g1[i][f] = dis[i] * relu(t[i]*W1[f] + b1[f]),  t[i] = dis[i]*(q[i]+p[i])
__global__ void k_g1(const float* __restrict__ dis, const float* __restrict__ p,
                     const float* __restrict__ q, const float* __restrict__ W1,
                     const float* __restrict__ b1, float* __restrict__ g1, int N) {
    int gid = blockIdx.x * blockDim.x + threadIdx.x;
    int node = gid >> 5;            // 32 float4-threads per node (128 feats)
    int f = (gid & 31) << 2;
    if (node >= N) return;
    float r = dis[node];
    float t = r * (q[node] + p[node]);
    float4 wv = *(const float4*)(W1 + f);
    float4 bv = *(const float4*)(b1 + f);
    float4 o;
    o.x = r * fmaxf(t * wv.x + bv.x, 0.0f);
    o.y = r * fmaxf(t * wv.y + bv.y, 0.0f);
    o.z = r * fmaxf(t * wv.z + bv.z, 0.0f);
    o.w = r * fmaxf(t * wv.w + bv.w, 0.0f);
    *(float4*)(g1 + (size_t)node * HD + f) = o;
}

// Wave per node: z[d][:] = dis[d] * (sum_e w_e*g1[src_e][:] + g1[d][:])
// Lane l covers features [2l, 2l+1]; edge (col,val) broadcast via shuffles.
__global__ __launch_bounds__(256) void k_agg(const int* __restrict__ rowptr,
                                             const int* __restrict__ col,
                                             const float* __restrict__ val,
                                             const float* __restrict__ dis,
                                             const float* __restrict__ g1,
                                             float* __restrict__ z, int N) {
    int wid = (blockIdx.x * blockDim.x + threadIdx.x) >> 6;
    int lane = threadIdx.x & 63;
    if (wid >= N) return;
    int beg = rowptr[wid], end = rowptr[wid + 1];
    float ax = 0.0f, ay = 0.0f;
    for (int base = beg; base < end; base += 64) {
        int eidx = base + lane;
        int cs = 0; float wv = 0.0f;
        if (eidx < end) { cs = col[eidx]; wv = val[eidx]; }
        int m = min(64, end - base);
        for (int j = 0; j < m; j++) {
            int s = __shfl(cs, j);
            float ww = __shfl(wv, j);
            float2 gv = *(const float2*)(g1 + (size_t)s * HD + lane * 2);
            ax += ww * gv.x;
            ay += ww * gv.y;
        }
    }
    float2 self = *(const float2*)(g1 + (size_t)wid * HD + lane * 2);
    float r = dis[wid];
    float2 o = { r * (ax + self.x), r * (ay + self.y) };
    *(float2*)(z + (size_t)wid * HD + lane * 2) = o;
}

// C[M x Ncols] = relu(A[M x K] @ B[K x Ncols] + bias). 128x128 tile, 8x8/thread.
template <int K>
__global__ __launch_bounds__(256) void k_gemm_relu(const float* __restrict__ A,
                                                   const float* __restrict__ B,
                                                   const float* __restrict__ bias,
                                                   float* __restrict__ C,
                                                   int M, int Ncols) {
    __shared__ float As[16][128];  // [k][m] (transposed for vector reads over m)
    __shared__ float Bs[16][128];  // [k][n]
    int tx = threadIdx.x & 15, ty = threadIdx.x >> 4;
    int row0 = blockIdx.x * 128, col0 = blockIdx.y * 128;
    float acc[8][8] = {};
    for (int kc = 0; kc < K; kc += 16) {
        int f4 = threadIdx.x * 2;
        for (int u = 0; u < 2; u++) {        // A tile: 128 rows x 16 k
            int id = f4 + u;
            int r = id >> 2, kk = (id & 3) << 2;
            int row = row0 + r;
            float4 v = (row < M) ? *(const float4*)(A + (size_t)row * K + kc + kk)
                                 : make_float4(0.f, 0.f, 0.f, 0.f);
            As[kk + 0][r] = v.x; As[kk + 1][r] = v.y;
            As[kk + 2][r] = v.z; As[kk + 3][r] = v.w;
        }
        for (int u = 0; u < 2; u++) {        // B tile: 16 k x 128 n
            int id = f4 + u;
            int kk = id >> 5, nn = (id & 31) << 2;
            *(float4*)(&Bs[kk][nn]) =
                *(const float4*)(B + (size_t)(kc + kk) * Ncols + col0 + nn);
        }
        __syncthreads();
        for (int k = 0; k < 16; k++) {
            float a[8], b[8];
            *(float4*)(a)     = *(float4*)(&As[k][ty * 8]);
            *(float4*)(a + 4) = *(float4*)(&As[k][ty * 8 + 4]);
            *(float4*)(b)     = *(float4*)(&Bs[k][tx * 8]);
            *(float4*)(b + 4) = *(float4*)(&Bs[k][tx * 8 + 4]);
            for (int i = 0; i < 8; i++)
                for (int j = 0; j < 8; j++)
                    acc[i][j] += a[i] * b[j];
        }
        __syncthreads();
    }
    float4 bv0 = *(const float4*)(bias + col0 + tx * 8);
    float4 bv1 = *(const float4*)(bias + col0 + tx * 8 + 4);
    for (int i = 0; i < 8; i++) {
        int row = row0 + ty * 8 + i;
        if (row >= M) continue;
        float4 o0, o1;
        o0.x = fmaxf(acc[i][0] + bv0.x, 0.f);
        o0.y = fmaxf(acc[i][1] + bv0.y, 0.f);
        o0.z = fmaxf(acc[i][2] + bv0.z, 0.f);
        o0.w = fmaxf(acc[i][3] + bv0.w, 0.f);
        o1.x = fmaxf(acc[i][4] + bv1.x, 0.f);
        o1.y = fmaxf(acc[i][5] + bv1.y, 0.f);
        o1.z = fmaxf(acc[i][6] + bv1.z, 0.f);
        o1.w = fmaxf(acc[i][7] + bv1.w, 0.f);
        float* cp = C + (size_t)row * Ncols + col0 + tx * 8;
        *(float4*)(cp) = o0;
        *(float4*)(cp + 4) = o1;
    }
}

// out[i] = h3[i][:] . Wl2 + bl2  (wave per node, shuffle reduce)
__global__ __launch_bounds__(256) void k_out(const float* __restrict__ h3,
                                             const float* __restrict__ Wl2,
                                             const float* __restrict__ bl2,
                                             float* __restrict__ out, int N) {
    int wid = (blockIdx.x * blockDim.x + threadIdx.x) >> 6;
    int lane = threadIdx.x & 63;
    if (wid >= N) return;
    float2 h = *(const float2*)(h3 + (size_t)wid * HD + lane * 2);
    float2 wv = *(const float2*)(Wl2 + lane * 2);
    float s = h.x * wv.x + h.y * wv.y;
    for (int off = 32; off > 0; off >>= 1) s += __shfl_down(s, off);
    if (lane == 0) out[wid] = s + bl2[0];
}

extern "C" void kernel_launch(void* const* d_in, const int* in_sizes, int n_in,
                              void* d_out, int out_size, void* d_ws, size_t ws_size,
                              hipStream_t stream) {
    const float* x   = (const float*)d_in[0];
    const int*   ei  = (const int*)d_in[1];
    const float* ew  = (const float*)d_in[2];
    const float* W1  = (const float*)d_in[3];
    const float* b1  = (const float*)d_in[4];
    const float* W2  = (const float*)d_in[5];
    const float* b2  = (const float*)d_in[6];
    const float* Wl1 = (const float*)d_in[7];
    const float* bl1 = (const float*)d_in[8];
    const float* Wl2 = (const float*)d_in[9];
    const float* bl2 = (const float*)d_in[10];
    float* out = (float*)d_out;
    const int N = in_sizes[0];
    const int E = in_sizes[2];

    char* w = (char*)d_ws;
    size_t off = 0;
    auto alloc = [&](size_t bytes) -> void* {
        void* p = w + off;
        off = align256(off + bytes);
        return p;
    };
    float* g1     = (float*)alloc((size_t)N * HD * 4);   // also reused as h3
    float* z      = (float*)alloc((size_t)N * HD * 4);
    float* h2     = (float*)alloc((size_t)N * HD2 * 4);
    float* deg    = (float*)alloc((size_t)N * 4);
    float* dis    = (float*)alloc((size_t)N * 4);
    float* p_     = (float*)alloc((size_t)N * 4);
    float* q      = (float*)alloc((size_t)N * 4);
    int*   cnt    = (int*)alloc((size_t)N * 4);
    int*   incl   = (int*)alloc((size_t)N * 4);
    int*   rowptr = (int*)alloc((size_t)(N + 1) * 4);
    int*   fill   = (int*)alloc((size_t)N * 4);
    int*   src32  = (int*)alloc((size_t)E * 4);
    int*   dst32  = (int*)alloc((size_t)E * 4);
    int*   colA   = (int*)alloc((size_t)E * 4);
    float* valA   = (float*)alloc((size_t)E * 4);
    const int nb = (N + 1023) / 1024;
    int*   bsum   = (int*)alloc((size_t)nb * 4);

    const int gE = (E + 255) / 256;
    const int gN = (N + 255) / 256;

    k_cvt_edges<<<gE, 256, 0, stream>>>(ei, src32, dst32, E);
    k_init<<<gN, 256, 0, stream>>>(deg, q, cnt, N);
    k_deg<<<gE, 256, 0, stream>>>(dst32, ew, deg, cnt, E);
    k_pdis<<<gN, 256, 0, stream>>>(x, deg, dis, p_, N);
    k_q<<<gE, 256, 0, stream>>>(src32, dst32, ew, p_, q, E);
    k_scan1<<<nb, 1024, 0, stream>>>(cnt, incl, bsum, N);
    k_scan2<<<1, 256, 0, stream>>>(bsum, nb);
    k_scan3<<<(N + 1 + 255) / 256, 256, 0, stream>>>(cnt, incl, bsum, rowptr, fill, N, E);
    k_fill<<<gE, 256, 0, stream>>>(src32, dst32, ew, rowptr, fill, colA, valA, E);
    k_g1<<<(N * 32 + 255) / 256, 256, 0, stream>>>(dis, p_, q, W1, b1, g1, N);
    k_agg<<<(N + 3) / 4, 256, 0, stream>>>(rowptr, colA, valA, dis, g1, z, N);
    k_gemm_relu<128><<<dim3((N + 127) / 128, 2), 256, 0, stream>>>(z, W2, b2, h2, N, HD2);
    k_gemm_relu<256><<<dim3((N + 127) / 128, 1), 256, 0, stream>>>(h2, Wl1, bl1, g1, N, HD);
    k_out<<<(N + 3) / 4, 256, 0, stream>>>(g1, Wl2, bl2, out, N);
}

// Round 2
// 584.873 us; speedup vs baseline: 1.3367x; 1.3367x over previous
//
#include <hip/hip_runtime.h>

// GCN on MI355X — round 2: scatter->gather restructure.
//  - Layer-1 propagation is rank-1 (x is [N,1]) -> scalar math only.
//  - deg and q computed by CSR *gather* (was: float atomic scatter, 2x141 us).
//  - CSR entries packed as 8B (col,val) pairs -> half the scatter/gather ops.
//  - Edge conversion + int histogram fused into one pass.
//  - Final dot (h3 @ Wl2) fused into GEMM2 epilogue via LDS reduction.
// ws: g1[N*128] | z[N*128] | h2[N*256] | dis,p,cnt,incl,rowptr,fill | src,dst | cv[E]

#define HD 128
#define HD2 256

static inline size_t align256(size_t x) { return (x + 255) & ~(size_t)255; }

// Canonicalize edge_index to int32 src/dst AND histogram dst (fused).
// Node ids < 2^31, nonneg: under int64 layout the odd int32 words are all 0.
__global__ void k_edges(const int* __restrict__ ei, int* __restrict__ src32,
                        int* __restrict__ dst32, int* __restrict__ cnt, int E) {
    int e = blockIdx.x * blockDim.x + threadIdx.x;
    if (e >= E) return;
    bool is64 = (ei[1] == 0) && (ei[3] == 0) && (ei[5] == 0) && (ei[7] == 0);
    int s, d;
    if (is64) { s = ei[2 * e]; d = ei[2 * (E + e)]; }
    else      { s = ei[e];     d = ei[E + e]; }
    src32[e] = s;
    dst32[e] = d;
    atomicAdd(&cnt[d], 1);
}

// --- 3-kernel exclusive scan of cnt[0..N) -> rowptr[0..N] ---
__global__ __launch_bounds__(1024) void k_scan1(const int* __restrict__ cnt,
                                                int* __restrict__ incl,
                                                int* __restrict__ bsum, int N) {
    __shared__ int s[1024];
    int t = threadIdx.x, i = blockIdx.x * 1024 + t;
    s[t] = (i < N) ? cnt[i] : 0;
    __syncthreads();
    for (int off = 1; off < 1024; off <<= 1) {
        int add = (t >= off) ? s[t - off] : 0;
        __syncthreads();
        s[t] += add;
        __syncthreads();
    }
    if (i < N) incl[i] = s[t];
    if (t == 1023) bsum[blockIdx.x] = s[t];
}

__global__ void k_scan2(int* __restrict__ bsum, int nb) {
    __shared__ int s[1024];
    int t = threadIdx.x;
    for (int i = t; i < nb; i += blockDim.x) s[i] = bsum[i];
    __syncthreads();
    if (t == 0) {
        int run = 0;
        for (int i = 0; i < nb; i++) { int v = s[i]; s[i] = run; run += v; }
    }
    __syncthreads();
    for (int i = t; i < nb; i += blockDim.x) bsum[i] = s[i];
}

__global__ void k_scan3(const int* __restrict__ cnt, const int* __restrict__ incl,
                        const int* __restrict__ bsum, int* __restrict__ rowptr,
                        int* __restrict__ fill, int N, int E) {
    int i = blockIdx.x * blockDim.x + threadIdx.x;
    if (i < N) {
        rowptr[i] = bsum[i >> 10] + incl[i] - cnt[i];
        fill[i] = 0;
    }
    if (i == N) rowptr[N] = E;
}

// Bucket-fill CSR: one 8B packed (col,val) store per edge.
__global__ void k_fill(const int* __restrict__ src, const int* __restrict__ dst,
                       const float* __restrict__ w, const int* __restrict__ rowptr,
                       int* __restrict__ fill, int2* __restrict__ cv, int E) {
    int e = blockIdx.x * blockDim.x + threadIdx.x;
    if (e < E) {
        int d = dst[e];
        int pos = rowptr[d] + atomicAdd(&fill[d], 1);
        cv[pos] = make_int2(src[e], __float_as_int(w[e]));
    }
}

// Wave per node: deg = 1 + sum(row val); dis = rsqrt(deg); p = dis * x.
__global__ __launch_bounds__(256) void k_deg_dis_p(const int* __restrict__ rowptr,
                                                   const int2* __restrict__ cv,
                                                   const float* __restrict__ x,
                                                   float* __restrict__ dis,
                                                   float* __restrict__ p, int N) {
    int wid = (blockIdx.x * blockDim.x + threadIdx.x) >> 6;
    int lane = threadIdx.x & 63;
    if (wid >= N) return;
    int beg = rowptr[wid], end = rowptr[wid + 1];
    float s = 0.0f;
    for (int i = beg + lane; i < end; i += 64) s += __int_as_float(cv[i].y);
    for (int off = 32; off > 0; off >>= 1) s += __shfl_xor(s, off);
    if (lane == 0) {
        float r = rsqrtf(1.0f + s);   // deg >= 1 (self loop, w >= 0)
        dis[wid] = r;
        p[wid] = r * x[wid];
    }
}

// Wave per node, fused: q = sum(val * p[col]); t = dis*(q+p);
// g1[i][f] = dis[i] * relu(t*W1[f] + b1[f])  (lane covers 2 feats).
__global__ __launch_bounds__(256) void k_q_g1(const int* __restrict__ rowptr,
                                              const int2* __restrict__ cv,
                                              const float* __restrict__ dis,
                                              const float* __restrict__ p,
                                              const float* __restrict__ W1,
                                              const float* __restrict__ b1,
                                              float* __restrict__ g1, int N) {
    int wid = (blockIdx.x * blockDim.x + threadIdx.x) >> 6;
    int lane = threadIdx.x & 63;
    if (wid >= N) return;
    int beg = rowptr[wid], end = rowptr[wid + 1];
    float s = 0.0f;
    for (int i = beg + lane; i < end; i += 64) {
        int2 pr = cv[i];
        s += __int_as_float(pr.y) * p[pr.x];
    }
    for (int off = 32; off > 0; off >>= 1) s += __shfl_xor(s, off);
    float r = dis[wid];
    float t = r * (s + p[wid]);
    float2 wv = *(const float2*)(W1 + lane * 2);
    float2 bv = *(const float2*)(b1 + lane * 2);
    float2 o;
    o.x = r * fmaxf(t * wv.x + bv.x, 0.0f);
    o.y = r * fmaxf(t * wv.y + bv.y, 0.0f);
    *(float2*)(g1 + (size_t)wid * HD + lane * 2) = o;
}

// Wave per node: z[d][:] = dis[d] * (sum_e w_e*g1[col_e][:] + g1[d][:])
__global__ __launch_bounds__(256) void k_agg(const int* __restrict__ rowptr,
                                             const int2* __restrict__ cv,
                                             const float* __restrict__ dis,
                                             const float* __restrict__ g1,
                                             float* __restrict__ z, int N) {
    int wid = (blockIdx.x * blockDim.x + threadIdx.x) >> 6;
    int lane = threadIdx.x & 63;
    if (wid >= N) return;
    int beg = rowptr[wid], end = rowptr[wid + 1];
    float ax = 0.0f, ay = 0.0f;
    for (int base = beg; base < end; base += 64) {
        int eidx = base + lane;
        int2 pr = make_int2(0, 0);
        if (eidx < end) pr = cv[eidx];
        int cs = pr.x;
        float wv = __int_as_float(pr.y);
        int m = min(64, end - base);
        for (int j = 0; j < m; j++) {
            int s = __shfl(cs, j);
            float ww = __shfl(wv, j);
            float2 gv = *(const float2*)(g1 + (size_t)s * HD + lane * 2);
            ax += ww * gv.x;
            ay += ww * gv.y;
        }
    }
    float2 self = *(const float2*)(g1 + (size_t)wid * HD + lane * 2);
    float r = dis[wid];
    float2 o = { r * (ax + self.x), r * (ay + self.y) };
    *(float2*)(z + (size_t)wid * HD + lane * 2) = o;
}

// C[M x Ncols] = relu(A[M x K] @ B[K x Ncols] + bias). 128x128 tile, 8x8/thread.
template <int K>
__global__ __launch_bounds__(256) void k_gemm_relu(const float* __restrict__ A,
                                                   const float* __restrict__ B,
                                                   const float* __restrict__ bias,
                                                   float* __restrict__ C,
                                                   int M, int Ncols) {
    __shared__ float As[16][128];  // [k][m]
    __shared__ float Bs[16][128];  // [k][n]
    int tx = threadIdx.x & 15, ty = threadIdx.x >> 4;
    int row0 = blockIdx.x * 128, col0 = blockIdx.y * 128;
    float acc[8][8] = {};
    for (int kc = 0; kc < K; kc += 16) {
        int f4 = threadIdx.x * 2;
        for (int u = 0; u < 2; u++) {
            int id = f4 + u;
            int r = id >> 2, kk = (id & 3) << 2;
            int row = row0 + r;
            float4 v = (row < M) ? *(const float4*)(A + (size_t)row * K + kc + kk)
                                 : make_float4(0.f, 0.f, 0.f, 0.f);
            As[kk + 0][r] = v.x; As[kk + 1][r] = v.y;
            As[kk + 2][r] = v.z; As[kk + 3][r] = v.w;
        }
        for (int u = 0; u < 2; u++) {
            int id = f4 + u;
            int kk = id >> 5, nn = (id & 31) << 2;
            *(float4*)(&Bs[kk][nn]) =
                *(const float4*)(B + (size_t)(kc + kk) * Ncols + col0 + nn);
        }
        __syncthreads();
        for (int k = 0; k < 16; k++) {
            float a[8], b[8];
            *(float4*)(a)     = *(float4*)(&As[k][ty * 8]);
            *(float4*)(a + 4) = *(float4*)(&As[k][ty * 8 + 4]);
            *(float4*)(b)     = *(float4*)(&Bs[k][tx * 8]);
            *(float4*)(b + 4) = *(float4*)(&Bs[k][tx * 8 + 4]);
            for (int i = 0; i < 8; i++)
                for (int j = 0; j < 8; j++)
                    acc[i][j] += a[i] * b[j];
        }
        __syncthreads();
    }
    float4 bv0 = *(const float4*)(bias + col0 + tx * 8);
    float4 bv1 = *(const float4*)(bias + col0 + tx * 8 + 4);
    for (int i = 0; i < 8; i++) {
        int row = row0 + ty * 8 + i;
        if (row >= M) continue;
        float4 o0, o1;
        o0.x = fmaxf(acc[i][0] + bv0.x, 0.f);
        o0.y = fmaxf(acc[i][1] + bv0.y, 0.f);
        o0.z = fmaxf(acc[i][2] + bv0.z, 0.f);
        o0.w = fmaxf(acc[i][3] + bv0.w, 0.f);
        o1.x = fmaxf(acc[i][4] + bv1.x, 0.f);
        o1.y = fmaxf(acc[i][5] + bv1.y, 0.f);
        o1.z = fmaxf(acc[i][6] + bv1.z, 0.f);
        o1.w = fmaxf(acc[i][7] + bv1.w, 0.f);
        float* cp = C + (size_t)row * Ncols + col0 + tx * 8;
        *(float4*)(cp) = o0;
        *(float4*)(cp + 4) = o1;
    }
}

// GEMM2 fused with final dot: out[row] = relu(A@Wl1+bl1)[row,:] . Wl2 + bl2.
// K=256, Ncols=128 (single col block). LDS reduction across tx for the dot.
__global__ __launch_bounds__(256) void k_gemm_out(const float* __restrict__ A,
                                                  const float* __restrict__ B,
                                                  const float* __restrict__ bias,
                                                  const float* __restrict__ wl2,
                                                  const float* __restrict__ bl2,
                                                  float* __restrict__ out, int M) {
    const int K = 256;
    __shared__ float As[16][128];
    __shared__ float Bs[16][128];
    __shared__ float red[128][17];
    int tx = threadIdx.x & 15, ty = threadIdx.x >> 4;
    int row0 = blockIdx.x * 128;
    float acc[8][8] = {};
    for (int kc = 0; kc < K; kc += 16) {
        int f4 = threadIdx.x * 2;
        for (int u = 0; u < 2; u++) {
            int id = f4 + u;
            int r = id >> 2, kk = (id & 3) << 2;
            int row = row0 + r;
            float4 v = (row < M) ? *(const float4*)(A + (size_t)row * K + kc + kk)
                                 : make_float4(0.f, 0.f, 0.f, 0.f);
            As[kk + 0][r] = v.x; As[kk + 1][r] = v.y;
            As[kk + 2][r] = v.z; As[kk + 3][r] = v.w;
        }
        for (int u = 0; u < 2; u++) {
            int id = f4 + u;
            int kk = id >> 5, nn = (id & 31) << 2;
            *(float4*)(&Bs[kk][nn]) =
                *(const float4*)(B + (size_t)(kc + kk) * 128 + nn);
        }
        __syncthreads();
        for (int k = 0; k < 16; k++) {
            float a[8], b[8];
            *(float4*)(a)     = *(float4*)(&As[k][ty * 8]);
            *(float4*)(a + 4) = *(float4*)(&As[k][ty * 8 + 4]);
            *(float4*)(b)     = *(float4*)(&Bs[k][tx * 8]);
            *(float4*)(b + 4) = *(float4*)(&Bs[k][tx * 8 + 4]);
            for (int i = 0; i < 8; i++)
                for (int j = 0; j < 8; j++)
                    acc[i][j] += a[i] * b[j];
        }
        __syncthreads();
    }
    float4 bv0 = *(const float4*)(bias + tx * 8);
    float4 bv1 = *(const float4*)(bias + tx * 8 + 4);
    float4 w20 = *(const float4*)(wl2 + tx * 8);
    float4 w21 = *(const float4*)(wl2 + tx * 8 + 4);
    for (int i = 0; i < 8; i++) {
        float s = fmaxf(acc[i][0] + bv0.x, 0.f) * w20.x
                + fmaxf(acc[i][1] + bv0.y, 0.f) * w20.y
                + fmaxf(acc[i][2] + bv0.z, 0.f) * w20.z
                + fmaxf(acc[i][3] + bv0.w, 0.f) * w20.w
                + fmaxf(acc[i][4] + bv1.x, 0.f) * w21.x
                + fmaxf(acc[i][5] + bv1.y, 0.f) * w21.y
                + fmaxf(acc[i][6] + bv1.z, 0.f) * w21.z
                + fmaxf(acc[i][7] + bv1.w, 0.f) * w21.w;
        red[ty * 8 + i][tx] = s;
    }
    __syncthreads();
    int tid = threadIdx.x;
    if (tid < 128) {
        int row = row0 + tid;
        if (row < M) {
            float s = 0.0f;
            for (int t = 0; t < 16; t++) s += red[tid][t];
            out[row] = s + bl2[0];
        }
    }
}

extern "C" void kernel_launch(void* const* d_in, const int* in_sizes, int n_in,
                              void* d_out, int out_size, void* d_ws, size_t ws_size,
                              hipStream_t stream) {
    const float* x   = (const float*)d_in[0];
    const int*   ei  = (const int*)d_in[1];
    const float* ew  = (const float*)d_in[2];
    const float* W1  = (const float*)d_in[3];
    const float* b1  = (const float*)d_in[4];
    const float* W2  = (const float*)d_in[5];
    const float* b2  = (const float*)d_in[6];
    const float* Wl1 = (const float*)d_in[7];
    const float* bl1 = (const float*)d_in[8];
    const float* Wl2 = (const float*)d_in[9];
    const float* bl2 = (const float*)d_in[10];
    float* out = (float*)d_out;
    const int N = in_sizes[0];
    const int E = in_sizes[2];

    char* w = (char*)d_ws;
    size_t off = 0;
    auto alloc = [&](size_t bytes) -> void* {
        void* p = w + off;
        off = align256(off + bytes);
        return p;
    };
    float* g1     = (float*)alloc((size_t)N * HD * 4);
    float* z      = (float*)alloc((size_t)N * HD * 4);
    float* h2     = (float*)alloc((size_t)N * HD2 * 4);
    float* dis    = (float*)alloc((size_t)N * 4);
    float* p_     = (float*)alloc((size_t)N * 4);
    int*   cnt    = (int*)alloc((size_t)N * 4);
    int*   incl   = (int*)alloc((size_t)N * 4);
    int*   rowptr = (int*)alloc((size_t)(N + 1) * 4);
    int*   fill   = (int*)alloc((size_t)N * 4);
    int*   src32  = (int*)alloc((size_t)E * 4);
    int*   dst32  = (int*)alloc((size_t)E * 4);
    int2*  cv     = (int2*)alloc((size_t)E * 8);
    const int nb = (N + 1023) / 1024;
    int*   bsum   = (int*)alloc((size_t)nb * 4);

    const int gE = (E + 255) / 256;

    hipMemsetAsync(cnt, 0, (size_t)N * 4, stream);
    k_edges<<<gE, 256, 0, stream>>>(ei, src32, dst32, cnt, E);
    k_scan1<<<nb, 1024, 0, stream>>>(cnt, incl, bsum, N);
    k_scan2<<<1, 256, 0, stream>>>(bsum, nb);
    k_scan3<<<(N + 1 + 255) / 256, 256, 0, stream>>>(cnt, incl, bsum, rowptr, fill, N, E);
    k_fill<<<gE, 256, 0, stream>>>(src32, dst32, ew, rowptr, fill, cv, E);
    k_deg_dis_p<<<(N + 3) / 4, 256, 0, stream>>>(rowptr, cv, x, dis, p_, N);
    k_q_g1<<<(N + 3) / 4, 256, 0, stream>>>(rowptr, cv, dis, p_, W1, b1, g1, N);
    k_agg<<<(N + 3) / 4, 256, 0, stream>>>(rowptr, cv, dis, g1, z, N);
    k_gemm_relu<128><<<dim3((N + 127) / 128, 2), 256, 0, stream>>>(z, W2, b2, h2, N, HD2);
    k_gemm_out<<<(N + 127) / 128, 256, 0, stream>>>(h2, Wl1, bl1, Wl2, bl2, out, N);
}

// Round 3
// 537.718 us; speedup vs baseline: 1.4539x; 1.0877x over previous
//
#include <hip/hip_runtime.h>

// GCN on MI355X — round 3: bf16 activations + MFMA GEMMs + fewer edge passes.
//  - g1/z/h2 stored bf16 (halves k_agg gather row: 512->256 B/edge).
//  - Dense layers via v_mfma_f32_16x16x32_bf16, fp32 accumulate.
//  - B weights pre-transposed into [K/8][NCOLS][8] chunk layout -> LDS staging
//    is a linear copy (coalesced global, conflict-free ds_write/ds_read).
//  - CSR build reads edge_index directly (no src32/dst32 round-trip).
//  - Final dot (h3 @ Wl2) stays fused in GEMM2 epilogue (fp32).

#define HD 128
#define HD2 256

typedef __attribute__((ext_vector_type(8))) short bf8_t;   // 8 x bf16 (4 VGPR)
typedef __attribute__((ext_vector_type(4))) float f32x4;

static inline size_t align256(size_t x) { return (x + 255) & ~(size_t)255; }

__device__ inline ushort f2bf(float f) {            // RNE f32 -> bf16
    uint u = __float_as_uint(f);
    uint r = u + 0x7fffu + ((u >> 16) & 1u);
    return (ushort)(r >> 16);
}
__device__ inline float bflo(uint p) { return __uint_as_float(p << 16); }
__device__ inline float bfhi(uint p) { return __uint_as_float(p & 0xffff0000u); }
__device__ inline uint packbf(float a, float b) {
    return (uint)f2bf(a) | ((uint)f2bf(b) << 16);
}

// Histogram of dst. Node ids < 2^31, nonneg: under int64 layout odd words are 0.
__global__ void k_hist(const int* __restrict__ ei, int* __restrict__ cnt, int E) {
    int e = blockIdx.x * blockDim.x + threadIdx.x;
    if (e >= E) return;
    bool is64 = (ei[1] == 0) && (ei[3] == 0) && (ei[5] == 0) && (ei[7] == 0);
    int d = is64 ? ei[2 * (E + e)] : ei[E + e];
    atomicAdd(&cnt[d], 1);
}

// --- 3-kernel exclusive scan of cnt[0..N) -> rowptr[0..N] ---
__global__ __launch_bounds__(1024) void k_scan1(const int* __restrict__ cnt,
                                                int* __restrict__ incl,
                                                int* __restrict__ bsum, int N) {
    __shared__ int s[1024];
    int t = threadIdx.x, i = blockIdx.x * 1024 + t;
    s[t] = (i < N) ? cnt[i] : 0;
    __syncthreads();
    for (int off = 1; off < 1024; off <<= 1) {
        int add = (t >= off) ? s[t - off] : 0;
        __syncthreads();
        s[t] += add;
        __syncthreads();
    }
    if (i < N) incl[i] = s[t];
    if (t == 1023) bsum[blockIdx.x] = s[t];
}

__global__ void k_scan2(int* __restrict__ bsum, int nb) {
    __shared__ int s[1024];
    int t = threadIdx.x;
    for (int i = t; i < nb; i += blockDim.x) s[i] = bsum[i];
    __syncthreads();
    if (t == 0) {
        int run = 0;
        for (int i = 0; i < nb; i++) { int v = s[i]; s[i] = run; run += v; }
    }
    __syncthreads();
    for (int i = t; i < nb; i += blockDim.x) bsum[i] = s[i];
}

__global__ void k_scan3(const int* __restrict__ cnt, const int* __restrict__ incl,
                        const int* __restrict__ bsum, int* __restrict__ rowptr,
                        int* __restrict__ fill, int N, int E) {
    int i = blockIdx.x * blockDim.x + threadIdx.x;
    if (i < N) {
        rowptr[i] = bsum[i >> 10] + incl[i] - cnt[i];
        fill[i] = 0;
    }
    if (i == N) rowptr[N] = E;
}

// Bucket-fill CSR straight from edge_index: one packed 8B (col,val) store/edge.
__global__ void k_fill(const int* __restrict__ ei, const float* __restrict__ w,
                       const int* __restrict__ rowptr, int* __restrict__ fill,
                       int2* __restrict__ cv, int E) {
    int e = blockIdx.x * blockDim.x + threadIdx.x;
    if (e >= E) return;
    bool is64 = (ei[1] == 0) && (ei[3] == 0) && (ei[5] == 0) && (ei[7] == 0);
    int s, d;
    if (is64) { s = ei[2 * e]; d = ei[2 * (E + e)]; }
    else      { s = ei[e];     d = ei[E + e]; }
    int pos = rowptr[d] + atomicAdd(&fill[d], 1);
    cv[pos] = make_int2(s, __float_as_int(w[e]));
}

// Pre-transpose weights to bf16 chunk layout Bt[(k>>3)*NCOLS*8 + n*8 + (k&7)].
__global__ void k_prepB(const float* __restrict__ W2, const float* __restrict__ Wl1,
                        ushort* __restrict__ Bt1, ushort* __restrict__ Bt2) {
    int o = blockIdx.x * blockDim.x + threadIdx.x;
    if (o >= 32768) return;
    {   // Bt1: K=128, NCOLS=256
        int k0 = o & 7, n = (o >> 3) & 255, k8 = o >> 11;
        Bt1[o] = f2bf(W2[(size_t)(k8 * 8 + k0) * 256 + n]);
    }
    {   // Bt2: K=256, NCOLS=128
        int k0 = o & 7, n = (o >> 3) & 127, k8 = o >> 10;
        Bt2[o] = f2bf(Wl1[(size_t)(k8 * 8 + k0) * 128 + n]);
    }
}

// Wave per node: deg = 1 + sum(row val); dis = rsqrt(deg); p = dis * x.
__global__ __launch_bounds__(256) void k_deg_dis_p(const int* __restrict__ rowptr,
                                                   const int2* __restrict__ cv,
                                                   const float* __restrict__ x,
                                                   float* __restrict__ dis,
                                                   float* __restrict__ p, int N) {
    int wid = (blockIdx.x * blockDim.x + threadIdx.x) >> 6;
    int lane = threadIdx.x & 63;
    if (wid >= N) return;
    int beg = rowptr[wid], end = rowptr[wid + 1];
    float s = 0.0f;
    for (int i = beg + lane; i < end; i += 64) s += __int_as_float(cv[i].y);
    for (int off = 32; off > 0; off >>= 1) s += __shfl_xor(s, off);
    if (lane == 0) {
        float r = rsqrtf(1.0f + s);
        dis[wid] = r;
        p[wid] = r * x[wid];
    }
}

// Wave per node, fused: q = sum(val*p[col]); t = dis*(q+p);
// g1[i][f] = dis * relu(t*W1[f]+b1[f]) stored bf16 (lane covers 2 feats).
__global__ __launch_bounds__(256) void k_q_g1(const int* __restrict__ rowptr,
                                              const int2* __restrict__ cv,
                                              const float* __restrict__ dis,
                                              const float* __restrict__ p,
                                              const float* __restrict__ W1,
                                              const float* __restrict__ b1,
                                              uint* __restrict__ g1, int N) {
    int wid = (blockIdx.x * blockDim.x + threadIdx.x) >> 6;
    int lane = threadIdx.x & 63;
    if (wid >= N) return;
    int beg = rowptr[wid], end = rowptr[wid + 1];
    float s = 0.0f;
    for (int i = beg + lane; i < end; i += 64) {
        int2 pr = cv[i];
        s += __int_as_float(pr.y) * p[pr.x];
    }
    for (int off = 32; off > 0; off >>= 1) s += __shfl_xor(s, off);
    float r = dis[wid];
    float t = r * (s + p[wid]);
    float2 wv = *(const float2*)(W1 + lane * 2);
    float2 bv = *(const float2*)(b1 + lane * 2);
    float ox = r * fmaxf(t * wv.x + bv.x, 0.0f);
    float oy = r * fmaxf(t * wv.y + bv.y, 0.0f);
    g1[(size_t)wid * 64 + lane] = packbf(ox, oy);
}

// Wave per node: z[d][:] = dis[d]*(sum_e w_e*g1[col_e][:] + g1[d][:]), bf16 io.
__global__ __launch_bounds__(256) void k_agg(const int* __restrict__ rowptr,
                                             const int2* __restrict__ cv,
                                             const float* __restrict__ dis,
                                             const uint* __restrict__ g1,
                                             uint* __restrict__ z, int N) {
    int wid = (blockIdx.x * blockDim.x + threadIdx.x) >> 6;
    int lane = threadIdx.x & 63;
    if (wid >= N) return;
    int beg = rowptr[wid], end = rowptr[wid + 1];
    float ax = 0.0f, ay = 0.0f;
    for (int base = beg; base < end; base += 64) {
        int eidx = base + lane;
        int2 pr = make_int2(0, 0);
        if (eidx < end) pr = cv[eidx];
        int cs = pr.x;
        float wv = __int_as_float(pr.y);
        int m = min(64, end - base);
        for (int j = 0; j < m; j++) {
            int s = __shfl(cs, j);
            float ww = __shfl(wv, j);
            uint gv = g1[(size_t)s * 64 + lane];
            ax += ww * bflo(gv);
            ay += ww * bfhi(gv);
        }
    }
    uint sv = g1[(size_t)wid * 64 + lane];
    float r = dis[wid];
    z[(size_t)wid * 64 + lane] = packbf(r * (ax + bflo(sv)), r * (ay + bfhi(sv)));
}

// MFMA GEMM: C[M][NCOLS] = relu(A[M][K] @ B + bias), bf16 in/out, fp32 acc.
// Bt is the [K/8][NCOLS][8] chunked-transposed bf16 weight. 128 rows/block.
template <int K, int NCOLS>
__global__ __launch_bounds__(256) void k_mfma_gemm(const ushort* __restrict__ A,
                                                   const ushort* __restrict__ Bt,
                                                   const float* __restrict__ bias,
                                                   ushort* __restrict__ C, int M) {
    const int NT = NCOLS / 16;
    __shared__ ushort Bs[64 * NCOLS];     // one 64-k chunk of B
    int tid = threadIdx.x;
    int wv = tid >> 6, lane = tid & 63;
    int l15 = lane & 15, quad = lane >> 4;
    int row0 = blockIdx.x * 128 + wv * 32;
    f32x4 acc[2][NT];
    for (int i = 0; i < 2; i++)
        for (int j = 0; j < NT; j++) acc[i][j] = (f32x4){0.f, 0.f, 0.f, 0.f};

    int r0 = row0 + l15;      r0 = r0 < M ? r0 : M - 1;   // clamp (stores guarded)
    int r1 = row0 + 16 + l15; r1 = r1 < M ? r1 : M - 1;

    for (int kc0 = 0; kc0 < K; kc0 += 64) {
        const uint4* gsrc = (const uint4*)(Bt + (size_t)kc0 * NCOLS);
        uint4* ldst = (uint4*)Bs;
        for (int i = tid; i < (64 * NCOLS) / 8; i += 256) ldst[i] = gsrc[i];
        __syncthreads();
        for (int k32 = 0; k32 < 64; k32 += 32) {
            int kg = kc0 + k32 + quad * 8;
            bf8_t a0 = *(const bf8_t*)(A + (size_t)r0 * K + kg);
            bf8_t a1 = *(const bf8_t*)(A + (size_t)r1 * K + kg);
            const ushort* bbase = Bs + ((size_t)((k32 >> 3) + quad) * NCOLS + l15) * 8;
            for (int nt = 0; nt < NT; nt++) {
                bf8_t b = *(const bf8_t*)(bbase + nt * 128);
                acc[0][nt] = __builtin_amdgcn_mfma_f32_16x16x32_bf16(a0, b, acc[0][nt], 0, 0, 0);
                acc[1][nt] = __builtin_amdgcn_mfma_f32_16x16x32_bf16(a1, b, acc[1][nt], 0, 0, 0);
            }
        }
        __syncthreads();
    }
    for (int mt = 0; mt < 2; mt++)
        for (int nt = 0; nt < NT; nt++) {
            int col = nt * 16 + l15;
            float bb = bias[col];
            for (int rg = 0; rg < 4; rg++) {
                int row = row0 + mt * 16 + quad * 4 + rg;
                if (row < M)
                    C[(size_t)row * NCOLS + col] = f2bf(fmaxf(acc[mt][nt][rg] + bb, 0.f));
            }
        }
}

// GEMM2 fused with final dot: out[row] = relu(A@Wl1+bl1)[row,:] . wl2 + bl2.
__global__ __launch_bounds__(256) void k_mfma_gemm_out(const ushort* __restrict__ A,
                                                       const ushort* __restrict__ Bt,
                                                       const float* __restrict__ bias,
                                                       const float* __restrict__ wl2,
                                                       const float* __restrict__ bl2,
                                                       float* __restrict__ out, int M) {
    const int K = 256, NCOLS = 128, NT = 8;
    __shared__ ushort Bs[64 * NCOLS];     // 16 KB
    __shared__ float red[128][17];        // cross-lane row reduction
    int tid = threadIdx.x;
    int wv = tid >> 6, lane = tid & 63;
    int l15 = lane & 15, quad = lane >> 4;
    int row0 = blockIdx.x * 128 + wv * 32;
    f32x4 acc[2][NT];
    for (int i = 0; i < 2; i++)
        for (int j = 0; j < NT; j++) acc[i][j] = (f32x4){0.f, 0.f, 0.f, 0.f};

    int r0 = row0 + l15;      r0 = r0 < M ? r0 : M - 1;
    int r1 = row0 + 16 + l15; r1 = r1 < M ? r1 : M - 1;

    for (int kc0 = 0; kc0 < K; kc0 += 64) {
        const uint4* gsrc = (const uint4*)(Bt + (size_t)kc0 * NCOLS);
        uint4* ldst = (uint4*)Bs;
        for (int i = tid; i < (64 * NCOLS) / 8; i += 256) ldst[i] = gsrc[i];
        __syncthreads();
        for (int k32 = 0; k32 < 64; k32 += 32) {
            int kg = kc0 + k32 + quad * 8;
            bf8_t a0 = *(const bf8_t*)(A + (size_t)r0 * K + kg);
            bf8_t a1 = *(const bf8_t*)(A + (size_t)r1 * K + kg);
            const ushort* bbase = Bs + ((size_t)((k32 >> 3) + quad) * NCOLS + l15) * 8;
            for (int nt = 0; nt < NT; nt++) {
                bf8_t b = *(const bf8_t*)(bbase + nt * 128);
                acc[0][nt] = __builtin_amdgcn_mfma_f32_16x16x32_bf16(a0, b, acc[0][nt], 0, 0, 0);
                acc[1][nt] = __builtin_amdgcn_mfma_f32_16x16x32_bf16(a1, b, acc[1][nt], 0, 0, 0);
            }
        }
        __syncthreads();
    }
    float rs[2][4] = {};
    for (int mt = 0; mt < 2; mt++)
        for (int nt = 0; nt < NT; nt++) {
            int col = nt * 16 + l15;
            float bb = bias[col], ww = wl2[col];
            for (int rg = 0; rg < 4; rg++)
                rs[mt][rg] += fmaxf(acc[mt][nt][rg] + bb, 0.f) * ww;
        }
    for (int mt = 0; mt < 2; mt++)
        for (int rg = 0; rg < 4; rg++)
            red[wv * 32 + mt * 16 + quad * 4 + rg][l15] = rs[mt][rg];
    __syncthreads();
    if (tid < 128) {
        int row = blockIdx.x * 128 + tid;
        if (row < M) {
            float s = 0.0f;
            for (int t = 0; t < 16; t++) s += red[tid][t];
            out[row] = s + bl2[0];
        }
    }
}

extern "C" void kernel_launch(void* const* d_in, const int* in_sizes, int n_in,
                              void* d_out, int out_size, void* d_ws, size_t ws_size,
                              hipStream_t stream) {
    const float* x   = (const float*)d_in[0];
    const int*   ei  = (const int*)d_in[1];
    const float* ew  = (const float*)d_in[2];
    const float* W1  = (const float*)d_in[3];
    const float* b1  = (const float*)d_in[4];
    const float* W2  = (const float*)d_in[5];
    const float* b2  = (const float*)d_in[6];
    const float* Wl1 = (const float*)d_in[7];
    const float* bl1 = (const float*)d_in[8];
    const float* Wl2 = (const float*)d_in[9];
    const float* bl2 = (const float*)d_in[10];
    float* out = (float*)d_out;
    const int N = in_sizes[0];
    const int E = in_sizes[2];

    char* w = (char*)d_ws;
    size_t off = 0;
    auto alloc = [&](size_t bytes) -> void* {
        void* p = w + off;
        off = align256(off + bytes);
        return p;
    };
    uint*   g1     = (uint*)alloc((size_t)N * 64 * 4);      // bf16 [N][128]
    uint*   z      = (uint*)alloc((size_t)N * 64 * 4);      // bf16 [N][128]
    ushort* h2     = (ushort*)alloc((size_t)N * HD2 * 2);   // bf16 [N][256]
    float*  dis    = (float*)alloc((size_t)N * 4);
    float*  p_     = (float*)alloc((size_t)N * 4);
    int*    cnt    = (int*)alloc((size_t)N * 4);
    int*    incl   = (int*)alloc((size_t)N * 4);
    int*    rowptr = (int*)alloc((size_t)(N + 1) * 4);
    int*    fill   = (int*)alloc((size_t)N * 4);
    int2*   cv     = (int2*)alloc((size_t)E * 8);
    ushort* Bt1    = (ushort*)alloc(32768 * 2);
    ushort* Bt2    = (ushort*)alloc(32768 * 2);
    const int nb = (N + 1023) / 1024;
    int*    bsum   = (int*)alloc((size_t)nb * 4);

    const int gE = (E + 255) / 256;

    hipMemsetAsync(cnt, 0, (size_t)N * 4, stream);
    k_hist<<<gE, 256, 0, stream>>>(ei, cnt, E);
    k_scan1<<<nb, 1024, 0, stream>>>(cnt, incl, bsum, N);
    k_scan2<<<1, 256, 0, stream>>>(bsum, nb);
    k_scan3<<<(N + 1 + 255) / 256, 256, 0, stream>>>(cnt, incl, bsum, rowptr, fill, N, E);
    k_fill<<<gE, 256, 0, stream>>>(ei, ew, rowptr, fill, cv, E);
    k_prepB<<<128, 256, 0, stream>>>(W2, Wl1, Bt1, Bt2);
    k_deg_dis_p<<<(N + 3) / 4, 256, 0, stream>>>(rowptr, cv, x, dis, p_, N);
    k_q_g1<<<(N + 3) / 4, 256, 0, stream>>>(rowptr, cv, dis, p_, W1, b1, g1, N);
    k_agg<<<(N + 3) / 4, 256, 0, stream>>>(rowptr, cv, dis, g1, z, N);
    k_mfma_gemm<128, 256><<<(N + 127) / 128, 256, 0, stream>>>((const ushort*)z, Bt1, b2, h2, N);
    k_mfma_gemm_out<<<(N + 127) / 128, 256, 0, stream>>>(h2, Bt2, bl1, Wl2, bl2, out, N);
}

// Round 4
// 441.277 us; speedup vs baseline: 1.7716x; 1.2186x over previous
//
#include <hip/hip_runtime.h>

// GCN on MI355X — round 4: fuse the entire MLP (GEMM1+GEMM2+final dot).
//  - Round-3 profile: k_mfma_gemm 131 us, WRITE_SIZE 361 MB vs 51 MB logical
//    (7x partial-sector write amplification on scalar bf16 C-stores).
//  - Fix: h2 never touches global. One kernel: z -> GEMM1(relu) -> per-wave
//    LDS C->A transform (32-col chunks) -> GEMM2(relu) -> dot wl2 -> out.
//  - B-fragments read directly from L2-resident chunked weights; no barriers.
//  - Graph side unchanged: CSR by counting sort, gather-based deg/q/agg.

#define HD 128
#define HD2 256

typedef __attribute__((ext_vector_type(8))) short bf8_t;   // 8 x bf16 (4 VGPR)
typedef __attribute__((ext_vector_type(4))) float f32x4;

static inline size_t align256(size_t x) { return (x + 255) & ~(size_t)255; }

__device__ inline ushort f2bf(float f) {            // RNE f32 -> bf16
    uint u = __float_as_uint(f);
    uint r = u + 0x7fffu + ((u >> 16) & 1u);
    return (ushort)(r >> 16);
}
__device__ inline float bflo(uint p) { return __uint_as_float(p << 16); }
__device__ inline float bfhi(uint p) { return __uint_as_float(p & 0xffff0000u); }
__device__ inline uint packbf(float a, float b) {
    return (uint)f2bf(a) | ((uint)f2bf(b) << 16);
}

// Histogram of dst. Node ids < 2^31, nonneg: under int64 layout odd words are 0.
__global__ void k_hist(const int* __restrict__ ei, int* __restrict__ cnt, int E) {
    int e = blockIdx.x * blockDim.x + threadIdx.x;
    if (e >= E) return;
    bool is64 = (ei[1] == 0) && (ei[3] == 0) && (ei[5] == 0) && (ei[7] == 0);
    int d = is64 ? ei[2 * (E + e)] : ei[E + e];
    atomicAdd(&cnt[d], 1);
}

// --- 3-kernel exclusive scan of cnt[0..N) -> rowptr[0..N] ---
__global__ __launch_bounds__(1024) void k_scan1(const int* __restrict__ cnt,
                                                int* __restrict__ incl,
                                                int* __restrict__ bsum, int N) {
    __shared__ int s[1024];
    int t = threadIdx.x, i = blockIdx.x * 1024 + t;
    s[t] = (i < N) ? cnt[i] : 0;
    __syncthreads();
    for (int off = 1; off < 1024; off <<= 1) {
        int add = (t >= off) ? s[t - off] : 0;
        __syncthreads();
        s[t] += add;
        __syncthreads();
    }
    if (i < N) incl[i] = s[t];
    if (t == 1023) bsum[blockIdx.x] = s[t];
}

__global__ void k_scan2(int* __restrict__ bsum, int nb) {
    __shared__ int s[1024];
    int t = threadIdx.x;
    for (int i = t; i < nb; i += blockDim.x) s[i] = bsum[i];
    __syncthreads();
    if (t == 0) {
        int run = 0;
        for (int i = 0; i < nb; i++) { int v = s[i]; s[i] = run; run += v; }
    }
    __syncthreads();
    for (int i = t; i < nb; i += blockDim.x) bsum[i] = s[i];
}

__global__ void k_scan3(const int* __restrict__ cnt, const int* __restrict__ incl,
                        const int* __restrict__ bsum, int* __restrict__ rowptr,
                        int* __restrict__ fill, int N, int E) {
    int i = blockIdx.x * blockDim.x + threadIdx.x;
    if (i < N) {
        rowptr[i] = bsum[i >> 10] + incl[i] - cnt[i];
        fill[i] = 0;
    }
    if (i == N) rowptr[N] = E;
}

// Bucket-fill CSR straight from edge_index: one packed 8B (col,val) store/edge.
__global__ void k_fill(const int* __restrict__ ei, const float* __restrict__ w,
                       const int* __restrict__ rowptr, int* __restrict__ fill,
                       int2* __restrict__ cv, int E) {
    int e = blockIdx.x * blockDim.x + threadIdx.x;
    if (e >= E) return;
    bool is64 = (ei[1] == 0) && (ei[3] == 0) && (ei[5] == 0) && (ei[7] == 0);
    int s, d;
    if (is64) { s = ei[2 * e]; d = ei[2 * (E + e)]; }
    else      { s = ei[e];     d = ei[E + e]; }
    int pos = rowptr[d] + atomicAdd(&fill[d], 1);
    cv[pos] = make_int2(s, __float_as_int(w[e]));
}

// Pre-transpose weights to bf16 chunk layout Bt[(k>>3)*NCOLS*8 + n*8 + (k&7)].
__global__ void k_prepB(const float* __restrict__ W2, const float* __restrict__ Wl1,
                        ushort* __restrict__ Bt1, ushort* __restrict__ Bt2) {
    int o = blockIdx.x * blockDim.x + threadIdx.x;
    if (o >= 32768) return;
    {   // Bt1: K=128, NCOLS=256
        int k0 = o & 7, n = (o >> 3) & 255, k8 = o >> 11;
        Bt1[o] = f2bf(W2[(size_t)(k8 * 8 + k0) * 256 + n]);
    }
    {   // Bt2: K=256, NCOLS=128
        int k0 = o & 7, n = (o >> 3) & 127, k8 = o >> 10;
        Bt2[o] = f2bf(Wl1[(size_t)(k8 * 8 + k0) * 128 + n]);
    }
}

// Wave per node: deg = 1 + sum(row val); dis = rsqrt(deg); p = dis * x.
__global__ __launch_bounds__(256) void k_deg_dis_p(const int* __restrict__ rowptr,
                                                   const int2* __restrict__ cv,
                                                   const float* __restrict__ x,
                                                   float* __restrict__ dis,
                                                   float* __restrict__ p, int N) {
    int wid = (blockIdx.x * blockDim.x + threadIdx.x) >> 6;
    int lane = threadIdx.x & 63;
    if (wid >= N) return;
    int beg = rowptr[wid], end = rowptr[wid + 1];
    float s = 0.0f;
    for (int i = beg + lane; i < end; i += 64) s += __int_as_float(cv[i].y);
    for (int off = 32; off > 0; off >>= 1) s += __shfl_xor(s, off);
    if (lane == 0) {
        float r = rsqrtf(1.0f + s);
        dis[wid] = r;
        p[wid] = r * x[wid];
    }
}

// Wave per node, fused: q = sum(val*p[col]); t = dis*(q+p);
// g1[i][f] = dis * relu(t*W1[f]+b1[f]) stored bf16 (lane covers 2 feats).
__global__ __launch_bounds__(256) void k_q_g1(const int* __restrict__ rowptr,
                                              const int2* __restrict__ cv,
                                              const float* __restrict__ dis,
                                              const float* __restrict__ p,
                                              const float* __restrict__ W1,
                                              const float* __restrict__ b1,
                                              uint* __restrict__ g1, int N) {
    int wid = (blockIdx.x * blockDim.x + threadIdx.x) >> 6;
    int lane = threadIdx.x & 63;
    if (wid >= N) return;
    int beg = rowptr[wid], end = rowptr[wid + 1];
    float s = 0.0f;
    for (int i = beg + lane; i < end; i += 64) {
        int2 pr = cv[i];
        s += __int_as_float(pr.y) * p[pr.x];
    }
    for (int off = 32; off > 0; off >>= 1) s += __shfl_xor(s, off);
    float r = dis[wid];
    float t = r * (s + p[wid]);
    float2 wv = *(const float2*)(W1 + lane * 2);
    float2 bv = *(const float2*)(b1 + lane * 2);
    float ox = r * fmaxf(t * wv.x + bv.x, 0.0f);
    float oy = r * fmaxf(t * wv.y + bv.y, 0.0f);
    g1[(size_t)wid * 64 + lane] = packbf(ox, oy);
}

// Wave per node: z[d][:] = dis[d]*(sum_e w_e*g1[col_e][:] + g1[d][:]), bf16 io.
__global__ __launch_bounds__(256) void k_agg(const int* __restrict__ rowptr,
                                             const int2* __restrict__ cv,
                                             const float* __restrict__ dis,
                                             const uint* __restrict__ g1,
                                             uint* __restrict__ z, int N) {
    int wid = (blockIdx.x * blockDim.x + threadIdx.x) >> 6;
    int lane = threadIdx.x & 63;
    if (wid >= N) return;
    int beg = rowptr[wid], end = rowptr[wid + 1];
    float ax = 0.0f, ay = 0.0f;
    for (int base = beg; base < end; base += 64) {
        int eidx = base + lane;
        int2 pr = make_int2(0, 0);
        if (eidx < end) pr = cv[eidx];
        int cs = pr.x;
        float wv = __int_as_float(pr.y);
        int m = min(64, end - base);
        for (int j = 0; j < m; j++) {
            int s = __shfl(cs, j);
            float ww = __shfl(wv, j);
            uint gv = g1[(size_t)s * 64 + lane];
            ax += ww * bflo(gv);
            ay += ww * bfhi(gv);
        }
    }
    uint sv = g1[(size_t)wid * 64 + lane];
    float r = dis[wid];
    z[(size_t)wid * 64 + lane] = packbf(r * (ax + bflo(sv)), r * (ay + bfhi(sv)));
}

// Fused MLP: out[i] = relu(relu(z[i]@W2+b2)@Wl1+bl1) . wl2 + bl2.
// 4 independent waves/block, 32 rows each. h2 lives only in regs + per-wave LDS.
// B-fragments come straight from L2-resident chunked weights (no staging).
__global__ __launch_bounds__(256) void k_mlp(const ushort* __restrict__ A,    // z bf16 [N][128]
                                             const ushort* __restrict__ Bt1,  // [16][256][8]
                                             const ushort* __restrict__ Bt2,  // [32][128][8]
                                             const float* __restrict__ b2,
                                             const float* __restrict__ bl1,
                                             const float* __restrict__ wl2,
                                             const float* __restrict__ bl2,
                                             float* __restrict__ out, int M) {
    __shared__ ushort st[4][32][40];   // per-wave C->A staging; 80B row stride
    int tid = threadIdx.x;
    int wv = tid >> 6, lane = tid & 63;
    int l15 = lane & 15, quad = lane >> 4;
    int row0 = blockIdx.x * 128 + wv * 32;
    int r0 = row0 + l15;      r0 = r0 < M ? r0 : M - 1;   // clamp; stores guarded
    int r1 = row0 + 16 + l15; r1 = r1 < M ? r1 : M - 1;

    bf8_t a1[2][4];                       // all A1 frags resident (32 VGPR)
    for (int kc = 0; kc < 4; kc++) {
        a1[0][kc] = *(const bf8_t*)(A + (size_t)r0 * 128 + kc * 32 + quad * 8);
        a1[1][kc] = *(const bf8_t*)(A + (size_t)r1 * 128 + kc * 32 + quad * 8);
    }
    f32x4 acc2[2][8];
    for (int i = 0; i < 2; i++)
        for (int j = 0; j < 8; j++) acc2[i][j] = (f32x4){0.f, 0.f, 0.f, 0.f};

    for (int c = 0; c < 8; c++) {         // 32-col chunk of h2 == 32-k of GEMM2
        f32x4 acc1[2][2];
        for (int i = 0; i < 2; i++)
            for (int j = 0; j < 2; j++) acc1[i][j] = (f32x4){0.f, 0.f, 0.f, 0.f};
        for (int kc = 0; kc < 4; kc++)
            for (int nt = 0; nt < 2; nt++) {
                bf8_t b = *(const bf8_t*)(Bt1 +
                    ((size_t)(kc * 4 + quad) * 256 + c * 32 + nt * 16 + l15) * 8);
                acc1[0][nt] = __builtin_amdgcn_mfma_f32_16x16x32_bf16(a1[0][kc], b, acc1[0][nt], 0, 0, 0);
                acc1[1][nt] = __builtin_amdgcn_mfma_f32_16x16x32_bf16(a1[1][kc], b, acc1[1][nt], 0, 0, 0);
            }
        // relu+bias, pack bf16, stage C-layout -> A-layout (wave-private LDS)
        for (int nt = 0; nt < 2; nt++) {
            float bb = b2[c * 32 + nt * 16 + l15];
            for (int mt = 0; mt < 2; mt++)
                for (int rg = 0; rg < 4; rg++)
                    st[wv][mt * 16 + quad * 4 + rg][nt * 16 + l15] =
                        f2bf(fmaxf(acc1[mt][nt][rg] + bb, 0.f));
        }
        bf8_t a2_0 = *(const bf8_t*)&st[wv][l15][quad * 8];
        bf8_t a2_1 = *(const bf8_t*)&st[wv][16 + l15][quad * 8];
        for (int nt2 = 0; nt2 < 8; nt2++) {
            bf8_t b = *(const bf8_t*)(Bt2 +
                ((size_t)(c * 4 + quad) * 128 + nt2 * 16 + l15) * 8);
            acc2[0][nt2] = __builtin_amdgcn_mfma_f32_16x16x32_bf16(a2_0, b, acc2[0][nt2], 0, 0, 0);
            acc2[1][nt2] = __builtin_amdgcn_mfma_f32_16x16x32_bf16(a2_1, b, acc2[1][nt2], 0, 0, 0);
        }
    }
    // epilogue: relu(+bl1) dot wl2, reduce across the 16-lane group, store
    float rs[2][4] = {};
    for (int nt2 = 0; nt2 < 8; nt2++) {
        int col = nt2 * 16 + l15;
        float bb = bl1[col], ww = wl2[col];
        for (int mt = 0; mt < 2; mt++)
            for (int rg = 0; rg < 4; rg++)
                rs[mt][rg] += fmaxf(acc2[mt][nt2][rg] + bb, 0.f) * ww;
    }
    float base = bl2[0];
    for (int mt = 0; mt < 2; mt++)
        for (int rg = 0; rg < 4; rg++) {
            float s = rs[mt][rg];
            s += __shfl_xor(s, 1);
            s += __shfl_xor(s, 2);
            s += __shfl_xor(s, 4);
            s += __shfl_xor(s, 8);
            int row = row0 + mt * 16 + quad * 4 + rg;
            if (l15 == 0 && row < M) out[row] = s + base;
        }
}

extern "C" void kernel_launch(void* const* d_in, const int* in_sizes, int n_in,
                              void* d_out, int out_size, void* d_ws, size_t ws_size,
                              hipStream_t stream) {
    const float* x   = (const float*)d_in[0];
    const int*   ei  = (const int*)d_in[1];
    const float* ew  = (const float*)d_in[2];
    const float* W1  = (const float*)d_in[3];
    const float* b1  = (const float*)d_in[4];
    const float* W2  = (const float*)d_in[5];
    const float* b2  = (const float*)d_in[6];
    const float* Wl1 = (const float*)d_in[7];
    const float* bl1 = (const float*)d_in[8];
    const float* Wl2 = (const float*)d_in[9];
    const float* bl2 = (const float*)d_in[10];
    float* out = (float*)d_out;
    const int N = in_sizes[0];
    const int E = in_sizes[2];

    char* w = (char*)d_ws;
    size_t off = 0;
    auto alloc = [&](size_t bytes) -> void* {
        void* p = w + off;
        off = align256(off + bytes);
        return p;
    };
    uint*   g1     = (uint*)alloc((size_t)N * 64 * 4);      // bf16 [N][128]
    uint*   z      = (uint*)alloc((size_t)N * 64 * 4);      // bf16 [N][128]
    float*  dis    = (float*)alloc((size_t)N * 4);
    float*  p_     = (float*)alloc((size_t)N * 4);
    int*    cnt    = (int*)alloc((size_t)N * 4);
    int*    incl   = (int*)alloc((size_t)N * 4);
    int*    rowptr = (int*)alloc((size_t)(N + 1) * 4);
    int*    fill   = (int*)alloc((size_t)N * 4);
    int2*   cv     = (int2*)alloc((size_t)E * 8);
    ushort* Bt1    = (ushort*)alloc(32768 * 2);
    ushort* Bt2    = (ushort*)alloc(32768 * 2);
    const int nb = (N + 1023) / 1024;
    int*    bsum   = (int*)alloc((size_t)nb * 4);

    const int gE = (E + 255) / 256;

    hipMemsetAsync(cnt, 0, (size_t)N * 4, stream);
    k_hist<<<gE, 256, 0, stream>>>(ei, cnt, E);
    k_scan1<<<nb, 1024, 0, stream>>>(cnt, incl, bsum, N);
    k_scan2<<<1, 256, 0, stream>>>(bsum, nb);
    k_scan3<<<(N + 1 + 255) / 256, 256, 0, stream>>>(cnt, incl, bsum, rowptr, fill, N, E);
    k_fill<<<gE, 256, 0, stream>>>(ei, ew, rowptr, fill, cv, E);
    k_prepB<<<128, 256, 0, stream>>>(W2, Wl1, Bt1, Bt2);
    k_deg_dis_p<<<(N + 3) / 4, 256, 0, stream>>>(rowptr, cv, x, dis, p_, N);
    k_q_g1<<<(N + 3) / 4, 256, 0, stream>>>(rowptr, cv, dis, p_, W1, b1, g1, N);
    k_agg<<<(N + 3) / 4, 256, 0, stream>>>(rowptr, cv, dis, g1, z, N);
    k_mlp<<<(N + 127) / 128, 256, 0, stream>>>((const ushort*)z, Bt1, Bt2,
                                               b2, bl1, Wl2, bl2, out, N);
}